// Round 10
// baseline (324.176 us; speedup 1.0000x reference)
//
#include <hip/hip_runtime.h>
#include <math.h>

#define NN 4096
#define SS 2048
#define DD 128
#define NADJ 2
#define MAXNNZ 64
#define HB 2048   // half-block width (cols per conv block)

typedef short v8s __attribute__((ext_vector_type(8)));
typedef float v4f __attribute__((ext_vector_type(4)));

__device__ __forceinline__ float softplusf(float x) {
    if (x > 20.f) return x;
    if (x < -20.f) return expf(x);
    return log1pf(expf(x));
}

__device__ __forceinline__ ushort f2bf(float f) {
    unsigned int u = __float_as_uint(f);
    unsigned int r = (u + 0x7fff + ((u >> 16) & 1)) >> 16;  // RNE
    return (ushort)r;
}
__device__ __forceinline__ float bf2f(ushort h) {
    return __uint_as_float(((unsigned int)h) << 16);
}
__device__ __forceinline__ float blo(unsigned int u) { return __uint_as_float(u << 16); }
__device__ __forceinline__ float bhi(unsigned int u) { return __uint_as_float(u & 0xffff0000u); }

// ---------------- params + zero sums ----------------
__global__ void params_kernel(const float* rls, const float* rvw, const float* rsw,
                              const float* rsb, const float* rsa, const float* rta,
                              float* params, double* sums) {
    if (threadIdx.x == 0) {
        float ls = softplusf(rls[0]);
        float vw = softplusf(rvw[0]);
        float sw = softplusf(rsw[0]);
        float sb = softplusf(rsb[0]);
        float a0 = softplusf(rsa[0]) * softplusf(rta[0]);
        float a1 = softplusf(rsa[1]) * softplusf(rta[1]);
        float vw2 = vw * vw, sw2 = sw * sw, sb2 = sb * sb;
        params[0] = 1.f / ls;
        params[1] = vw2 * sb2 * (a0 + a1);  // c_add
        params[2] = vw2 * sw2 * a0;         // w0
        params[3] = vw2 * sw2 * a1;         // w1
        sums[0] = 0.0; sums[1] = 0.0; sums[2] = 0.0;
    }
}

// ---------------- xb = bf16(feat/ls), xn = ||xb_row||^2 ----------------
__global__ void xb_kernel(const float* feat, const float* params, ushort* xb, float* xn) {
    int r = blockIdx.x;
    int l = threadIdx.x;  // 64 lanes
    float inv_ls = params[0];
    ushort h0 = f2bf(feat[r * DD + l] * inv_ls);
    ushort h1 = f2bf(feat[r * DD + 64 + l] * inv_ls);
    xb[r * DD + l] = h0;
    xb[r * DD + 64 + l] = h1;
    float v0 = bf2f(h0), v1 = bf2f(h1);
    float s = v0 * v0 + v1 * v1;
    for (int off = 32; off; off >>= 1) s += __shfl_xor(s, off);
    if (l == 0) xn[r] = s;
}

// ---------------- C0 = bf16(exp(-0.5 * sqdist)) via bf16 MFMA ----------------
__global__ __launch_bounds__(256) void c0_mfma_kernel(const ushort* xb, const float* xn,
                                                      ushort* C0b) {
    __shared__ float xr[128], xc[128];
    int t = threadIdx.x;
    int r0 = blockIdx.y * 128, c0 = blockIdx.x * 128;
    if (t < 128) xr[t] = xn[r0 + t];
    else xc[t - 128] = xn[c0 + (t - 128)];
    __syncthreads();

    int w = t >> 6, l = t & 63;
    int wr = w >> 1, wc = w & 1;
    int lr = l & 15;
    int lk = (l >> 4) * 8;
    const ushort* pa = xb + (size_t)(r0 + wr * 64 + lr) * DD + lk;
    const ushort* pb = xb + (size_t)(c0 + wc * 64 + lr) * DD + lk;

    v4f acc[4][4] = {};
    for (int ks = 0; ks < 4; ks++) {
        v8s a[4], b[4];
        for (int m = 0; m < 4; m++) a[m] = *(const v8s*)(pa + (size_t)m * 16 * DD + ks * 32);
        for (int n = 0; n < 4; n++) b[n] = *(const v8s*)(pb + (size_t)n * 16 * DD + ks * 32);
        for (int m = 0; m < 4; m++)
            for (int n = 0; n < 4; n++)
                acc[m][n] = __builtin_amdgcn_mfma_f32_16x16x32_bf16(a[m], b[n], acc[m][n], 0, 0, 0);
    }

    int rbase = wr * 64;
    int cbase = wc * 64;
    for (int m = 0; m < 4; m++) {
        for (int n = 0; n < 4; n++) {
            int ocol = cbase + n * 16 + lr;
            float xnc = xc[ocol];
            for (int j = 0; j < 4; j++) {
                int orow = rbase + m * 16 + (l >> 4) * 4 + j;
                float sq = xr[orow] + xnc - 2.f * acc[m][n][j];
                sq = fmaxf(sq, 0.f);
                C0b[(size_t)(r0 + orow) * NN + c0 + ocol] = f2bf(expf(-0.5f * sq));
            }
        }
    }
}

// ---------------- CSR extraction (block-masked), deterministic ----------------
__global__ void extract_kernel(const float* adj, int* nnzc, int* colsa) {
    __shared__ int sc[MAXNNZ];
    int b = blockIdx.x;        // a*NN + r
    int i = b >> 12;
    int r = b & (NN - 1);
    int lane = threadIdx.x;    // 64
    int base = (r < SS) ? 0 : SS;
    const float* arow = adj + ((size_t)i * NN + r) * NN + base;
    int cnt = 0;
    for (int it = 0; it < SS / 64; ++it) {
        int c = it * 64 + lane;
        float v = arow[c];
        unsigned long long m = __ballot(v != 0.f);
        if (v != 0.f) {
            int pos = cnt + __popcll(m & ((1ull << lane) - 1ull));
            if (pos < MAXNNZ) sc[pos] = c;  // relative col
        }
        cnt += __popcll(m);
    }
    if (cnt > MAXNNZ) cnt = MAXNNZ;
    __syncthreads();
    if (lane < cnt) colsa[(size_t)b * MAXNNZ + lane] = base + sc[lane];
    if (lane == 0) nnzc[b] = cnt;
}

// ---------------- merge both adjacencies into one byte-offset list per col ----------------
__global__ void merge_kernel(const int* nnzc, const int* colsa, ushort* moff, ushort* colinfo) {
    int c = blockIdx.x * 256 + threadIdx.x;
    if (c >= NN) return;
    int base = (c < SS) ? 0 : SS;
    int n0 = nnzc[c], n1 = nnzc[NN + c];
    int c0 = n0 < 8 ? n0 : 8;
    int c1 = n1 < 8 ? n1 : 8;
    ushort e[16];
    #pragma unroll
    for (int i = 0; i < 16; i++) e[i] = 8192;
    for (int i = 0; i < c0; i++)
        e[i] = (ushort)((colsa[(size_t)c * MAXNNZ + i] - base) * 4);
    for (int i = 0; i < c1; i++)
        e[c0 + i] = (ushort)((2056 + colsa[(size_t)(NN + c) * MAXNNZ + i] - base) * 4);
    uint4* mo = (uint4*)(moff + (size_t)c * 16);
    mo[0] = *(uint4*)&e[0];
    mo[1] = *(uint4*)&e[8];
    colinfo[c] = (ushort)((n0 > 8 || n1 > 8) ? 1 : 0);
}

// ---------------- diag of layer-1 K -> svec (double gather on bf16 C0) ----------------
__global__ void diag1_kernel(const ushort* C0b, const int* nnzc, const int* colsa,
                             const float* params, float* svec) {
    int t = threadIdx.x;
    int r = blockIdx.x * 4 + (t >> 6);
    int lane = t & 63;
    float c_add = params[1], w0 = params[2], w1 = params[3];
    float s = 0.f;
    for (int a = 0; a < 2; a++) {
        int b = a * NN + r;
        int cnt = nnzc[b];
        const int* crow = colsa + (size_t)b * MAXNNZ;
        int myk = crow[(lane < cnt) ? lane : 0];
        float wa = a ? w1 : w0;
        float acc = 0.f;
        for (int j = 0; j < cnt; j++) {
            int row = crow[j];
            if (lane < cnt) acc += bf2f(C0b[(size_t)row * NN + myk]);
        }
        s += wa * acc;
    }
    for (int off = 32; off; off >>= 1) s += __shfl_xor(s, off);
    if (lane == 0) {
        float d = c_add + s;
        svec[r] = sqrtf(fmaxf(d, 0.f)) + 1e-5f;
    }
}

// ---------------- fused conv, UPPER TRIANGLE only, 4-col interleaved gather ----------------
// zones (blockIdx.x): 0: r=by (<S), h=0, cols c_rel>=by   (ss upper)
//                     1: r=by (<S), h=1, full span        (st)
//                     2: r=S+by,    h=1, cols c_rel>=by   (tt upper)
template <int MODE>
__global__ __launch_bounds__(256, 8) void conv_kernel(const ushort* __restrict__ Kb,
                                                      const int* __restrict__ nnzc,
                                                      const int* __restrict__ colsa,
                                                      const uint* __restrict__ moffw,
                                                      const ushort* __restrict__ colinfo,
                                                      const float* __restrict__ params,
                                                      const float* __restrict__ svec,
                                                      void* __restrict__ Kout_,
                                                      double* __restrict__ sums) {
    __shared__ float rs[4112];
    __shared__ double red[256];
    int zone = blockIdx.x;
    int by = blockIdx.y;
    int r = (zone == 2) ? SS + by : by;
    int h = (zone >= 1) ? 1 : 0;
    int cstart = (zone == 1) ? 0 : by;
    int cbase = h * HB;
    int t = threadIdx.x;
    float c_add = params[1], w0 = params[2], w1 = params[3];

    // ---- rowsum (simple sequential streams; proven not the limiter) ----
    {
        float acc0[8], acc1[8];
        #pragma unroll
        for (int e = 0; e < 8; e++) { acc0[e] = 0.f; acc1[e] = 0.f; }
        int cnt0 = nnzc[r], cnt1 = nnzc[NN + r];
        const int* crow0 = colsa + (size_t)r * MAXNNZ;
        const int* crow1 = colsa + (size_t)(NN + r) * MAXNNZ;
        for (int j = 0; j < cnt0; j++) {
            uint4 v = *(const uint4*)(Kb + (size_t)crow0[j] * NN + cbase + t * 8);
            acc0[0] += blo(v.x); acc0[1] += bhi(v.x);
            acc0[2] += blo(v.y); acc0[3] += bhi(v.y);
            acc0[4] += blo(v.z); acc0[5] += bhi(v.z);
            acc0[6] += blo(v.w); acc0[7] += bhi(v.w);
        }
        for (int j = 0; j < cnt1; j++) {
            uint4 v = *(const uint4*)(Kb + (size_t)crow1[j] * NN + cbase + t * 8);
            acc1[0] += blo(v.x); acc1[1] += bhi(v.x);
            acc1[2] += blo(v.y); acc1[3] += bhi(v.y);
            acc1[4] += blo(v.z); acc1[5] += bhi(v.z);
            acc1[6] += blo(v.w); acc1[7] += bhi(v.w);
        }
        *(float4*)&rs[8 * t]            = {acc0[0]*w0, acc0[1]*w0, acc0[2]*w0, acc0[3]*w0};
        *(float4*)&rs[8 * t + 4]        = {acc0[4]*w0, acc0[5]*w0, acc0[6]*w0, acc0[7]*w0};
        *(float4*)&rs[2056 + 8 * t]     = {acc1[0]*w1, acc1[1]*w1, acc1[2]*w1, acc1[3]*w1};
        *(float4*)&rs[2056 + 8 * t + 4] = {acc1[4]*w1, acc1[5]*w1, acc1[6]*w1, acc1[7]*w1};
        if (t < 8) { rs[2048 + t] = 0.f; rs[4104 + t] = 0.f; }
    }
    __syncthreads();

    // ---- gather: 4 cols interleaved; each GSTEP issues 8 independent LDS reads ----
    float sr = (MODE == 0) ? svec[r] : 0.f;
    double dsum = 0.0;
    ushort* out_b = (ushort*)Kout_;
    float* out_f = (float*)Kout_;
    const char* rsb = (const char*)rs;
    int n_u = (HB - cstart + 255) >> 8;  // uniform slot count

    #pragma unroll
    for (int g = 0; g < 2; g++) {
        if (g * 4 >= n_u) break;  // uniform
        int cr0 = cstart + t + 256 * (g * 4 + 0);
        int cr1 = cstart + t + 256 * (g * 4 + 1);
        int cr2 = cstart + t + 256 * (g * 4 + 2);
        int cr3 = cstart + t + 256 * (g * 4 + 3);
        int col0 = cbase + (cr0 < HB ? cr0 : 0);
        int col1 = cbase + (cr1 < HB ? cr1 : 0);
        int col2 = cbase + (cr2 < HB ? cr2 : 0);
        int col3 = cbase + (cr3 < HB ? cr3 : 0);
        const uint* q0 = moffw + (size_t)col0 * 8;
        const uint* q1 = moffw + (size_t)col1 * 8;
        const uint* q2 = moffw + (size_t)col2 * 8;
        const uint* q3 = moffw + (size_t)col3 * 8;
        float ac0 = 0.f, ac1 = 0.f, ac2 = 0.f, ac3 = 0.f;
        #define GSTEP(k)                                                   \
        {                                                                  \
            uint w0 = q0[k], w1 = q1[k], w2 = q2[k], w3 = q3[k];           \
            float x0 = *(const float*)(rsb + (w0 & 0xffffu));              \
            float x1 = *(const float*)(rsb + (w1 & 0xffffu));              \
            float x2 = *(const float*)(rsb + (w2 & 0xffffu));              \
            float x3 = *(const float*)(rsb + (w3 & 0xffffu));              \
            float y0 = *(const float*)(rsb + (w0 >> 16));                  \
            float y1 = *(const float*)(rsb + (w1 >> 16));                  \
            float y2 = *(const float*)(rsb + (w2 >> 16));                  \
            float y3 = *(const float*)(rsb + (w3 >> 16));                  \
            ac0 += x0 + y0; ac1 += x1 + y1; ac2 += x2 + y2; ac3 += x3 + y3;\
        }
        GSTEP(0) GSTEP(1) GSTEP(2) GSTEP(3) GSTEP(4) GSTEP(5) GSTEP(6) GSTEP(7)
        #undef GSTEP
        ushort ci0 = colinfo[col0], ci1 = colinfo[col1];
        ushort ci2 = colinfo[col2], ci3 = colinfo[col3];

        #define EPI(ac, cr, col, ci)                                             \
        if ((cr) < HB) {                                                         \
            float acc = ac;                                                      \
            if ((ci) & 1) {                                                      \
                for (int a = 0; a < 2; a++) {                                    \
                    int b = a * NN + (col);                                      \
                    int cnt = nnzc[b];                                           \
                    if (cnt > 8) {                                               \
                        const int* cp = colsa + (size_t)b * MAXNNZ;              \
                        for (int k = 8; k < cnt; k++)                            \
                            acc += rs[(cp[k] & (HB - 1)) + (a ? 2056 : 0)];      \
                    }                                                            \
                }                                                                \
            }                                                                    \
            float kv = c_add + acc;                                              \
            if (MODE == 0) {                                                     \
                float pp = sr * svec[col];                                       \
                float cc = kv / pp;                                              \
                cc = fminf(fmaxf(cc, -1.f + 1e-6f), 1.f - 1e-6f);                \
                float th = acosf(cc);                                            \
                float sth = sqrtf(fmaxf(1.f - cc * cc, 0.f));                    \
                kv = 0.15915494309189535f *                                      \
                     (sth + (3.14159265358979323846f - th) * cc) * pp;           \
                out_b[(size_t)r * NN + (col)] = f2bf(kv);                        \
            } else {                                                             \
                out_f[(size_t)r * NN + (col)] = kv;                              \
                if (zone == 1) dsum += (double)kv;                               \
                else dsum += ((cr) == by) ? (double)kv : 2.0 * (double)kv;       \
            }                                                                    \
        }
        EPI(ac0, cr0, col0, ci0)
        EPI(ac1, cr1, col1, ci1)
        EPI(ac2, cr2, col2, ci2)
        EPI(ac3, cr3, col3, ci3)
        #undef EPI
    }

    if (MODE == 1) {
        red[t] = dsum;
        __syncthreads();
        for (int off = 128; off; off >>= 1) {
            if (t < off) red[t] += red[t + off];
            __syncthreads();
        }
        if (t == 0) atomicAdd(&sums[zone], red[0]);  // zone0->ss, zone1->st, zone2->tt
    }
}

// ---------------- mirror bf16 upper -> lower (tiled LDS transpose) ----------------
__global__ __launch_bounds__(256) void mirror_kernel(ushort* Kb) {
    int bi = blockIdx.x;
    int bj = blockIdx.y;
    if (bj < bi) return;
    __shared__ ushort lds[64][66];
    int R0 = bi * 64, C0 = bj * 64;
    int t = threadIdx.x;
    #pragma unroll
    for (int k = 0; k < 16; k++) {
        int lin = k * 256 + t;
        int row = lin >> 6, col = lin & 63;
        lds[row][col] = Kb[(size_t)(R0 + row) * NN + C0 + col];
    }
    __syncthreads();
    if (bj > bi) {
        #pragma unroll
        for (int k = 0; k < 16; k++) {
            int lin = k * 256 + t;
            int row = lin >> 6, col = lin & 63;
            Kb[(size_t)(C0 + row) * NN + R0 + col] = lds[col][row];
        }
    } else {
        #pragma unroll
        for (int k = 0; k < 16; k++) {
            int lin = k * 256 + t;
            int row = lin >> 6, col = lin & 63;
            if (row > col) Kb[(size_t)(R0 + row) * NN + R0 + col] = lds[col][row];
        }
    }
}

// ---------------- finalize: scale upper in place + write scaled transpose to lower ----------------
__global__ __launch_bounds__(256) void finalize_kernel(float* out, const double* sums) {
    int bi = blockIdx.x;
    int bj = blockIdx.y;
    if (bj < bi) return;
    __shared__ float lds[64][65];
    const double inv = 1.0 / (2048.0 * 2048.0);
    float mss = (float)(sums[0] * inv);
    float mst = (float)(sums[1] * inv);
    float mtt = (float)(sums[2] * inv);
    int R0 = bi * 64, C0 = bj * 64;
    float m = (R0 < SS) ? (C0 < SS ? mss : mst) : (C0 < SS ? mst : mtt);
    int t = threadIdx.x;
    #pragma unroll
    for (int k = 0; k < 16; k++) {
        int lin = k * 256 + t;
        int row = lin >> 6, col = lin & 63;
        lds[row][col] = out[(size_t)(R0 + row) * NN + C0 + col];
    }
    __syncthreads();
    if (bj > bi) {
        #pragma unroll
        for (int k = 0; k < 16; k++) {
            int lin = k * 256 + t;
            int row = lin >> 6, col = lin & 63;
            out[(size_t)(R0 + row) * NN + C0 + col] = m * lds[row][col];
            out[(size_t)(C0 + row) * NN + R0 + col] = m * lds[col][row];
        }
    } else {
        #pragma unroll
        for (int k = 0; k < 16; k++) {
            int lin = k * 256 + t;
            int row = lin >> 6, col = lin & 63;
            float v = (row <= col) ? lds[row][col] : lds[col][row];
            out[(size_t)(R0 + row) * NN + R0 + col] = m * v;
        }
    }
}

extern "C" void kernel_launch(void* const* d_in, const int* in_sizes, int n_in,
                              void* d_out, int out_size, void* d_ws, size_t ws_size,
                              hipStream_t stream) {
    const float* feat = (const float*)d_in[0];
    const float* adj  = (const float*)d_in[1];
    const float* rls  = (const float*)d_in[2];
    const float* rvw  = (const float*)d_in[3];
    const float* rsw  = (const float*)d_in[4];
    const float* rsb  = (const float*)d_in[5];
    const float* rsa  = (const float*)d_in[6];
    const float* rta  = (const float*)d_in[7];
    float* out = (float*)d_out;

    const size_t PNN = (size_t)NN * NN;
    char* p = (char*)d_ws;
    auto alloc = [&](size_t bytes) {
        char* r = p;
        p += (bytes + 255) & ~(size_t)255;
        return r;
    };
    float*  params   = (float*)alloc(64);
    double* sums     = (double*)alloc(64);
    float*  xn       = (float*)alloc((size_t)NN * 4);
    float*  svec     = (float*)alloc((size_t)NN * 4);
    int*    nnzc     = (int*)alloc((size_t)2 * NN * 4);
    int*    colsa    = (int*)alloc((size_t)2 * NN * MAXNNZ * 4);
    ushort* moff     = (ushort*)alloc((size_t)NN * 16 * 2);
    ushort* colinfo  = (ushort*)alloc((size_t)NN * 2);
    ushort* xb       = (ushort*)alloc((size_t)NN * DD * 2);
    ushort* cb0      = (ushort*)alloc(PNN * 2);   // 32 MiB bf16 C0
    ushort* kb1      = (ushort*)alloc(PNN * 2);   // 32 MiB bf16 relu(K1)

    params_kernel<<<1, 64, 0, stream>>>(rls, rvw, rsw, rsb, rsa, rta, params, sums);
    xb_kernel<<<NN, 64, 0, stream>>>(feat, params, xb, xn);
    c0_mfma_kernel<<<dim3(NN / 128, NN / 128), 256, 0, stream>>>(xb, xn, cb0);
    extract_kernel<<<NADJ * NN, 64, 0, stream>>>(adj, nnzc, colsa);
    merge_kernel<<<(NN + 255) / 256, 256, 0, stream>>>(nnzc, colsa, moff, colinfo);

    // svec = sqrt(diag(layer1 K)) from double-gather on C0
    diag1_kernel<<<NN / 4, 256, 0, stream>>>(cb0, nnzc, colsa, params, svec);

    // layer 1 (upper only): C0 (bf16) -> relu_cov(K1) (bf16), then mirror to full
    conv_kernel<0><<<dim3(3, HB), 256, 0, stream>>>(cb0, nnzc, colsa, (const uint*)moff,
                                                    colinfo, params, svec, kb1, sums);
    mirror_kernel<<<dim3(64, 64), 256, 0, stream>>>(kb1);

    // layer 2 (upper only): K1 (bf16) -> unscaled K2 (fp32) in d_out + block sums
    conv_kernel<1><<<dim3(3, HB), 256, 0, stream>>>(kb1, nnzc, colsa, (const uint*)moff,
                                                    colinfo, params, svec, out, sums);

    // scale by block means + fill lower triangle (transpose)
    finalize_kernel<<<dim3(64, 64), 256, 0, stream>>>(out, sums);
}

// Round 11
// 300.631 us; speedup vs baseline: 1.0783x; 1.0783x over previous
//
#include <hip/hip_runtime.h>
#include <math.h>

#define NN 4096
#define SS 2048
#define DD 128
#define NADJ 2
#define MAXNNZ 64
#define HB 2048   // half-block width (cols per conv block)

typedef short v8s __attribute__((ext_vector_type(8)));
typedef float v4f __attribute__((ext_vector_type(4)));

__device__ __forceinline__ float softplusf(float x) {
    if (x > 20.f) return x;
    if (x < -20.f) return expf(x);
    return log1pf(expf(x));
}

__device__ __forceinline__ ushort f2bf(float f) {
    unsigned int u = __float_as_uint(f);
    unsigned int r = (u + 0x7fff + ((u >> 16) & 1)) >> 16;  // RNE
    return (ushort)r;
}
__device__ __forceinline__ float bf2f(ushort h) {
    return __uint_as_float(((unsigned int)h) << 16);
}
__device__ __forceinline__ float blo(unsigned int u) { return __uint_as_float(u << 16); }
__device__ __forceinline__ float bhi(unsigned int u) { return __uint_as_float(u & 0xffff0000u); }

// ---------------- params + zero sums ----------------
__global__ void params_kernel(const float* rls, const float* rvw, const float* rsw,
                              const float* rsb, const float* rsa, const float* rta,
                              float* params, double* sums) {
    if (threadIdx.x == 0) {
        float ls = softplusf(rls[0]);
        float vw = softplusf(rvw[0]);
        float sw = softplusf(rsw[0]);
        float sb = softplusf(rsb[0]);
        float a0 = softplusf(rsa[0]) * softplusf(rta[0]);
        float a1 = softplusf(rsa[1]) * softplusf(rta[1]);
        float vw2 = vw * vw, sw2 = sw * sw, sb2 = sb * sb;
        params[0] = 1.f / ls;
        params[1] = vw2 * sb2 * (a0 + a1);  // c_add
        params[2] = vw2 * sw2 * a0;         // w0
        params[3] = vw2 * sw2 * a1;         // w1
        sums[0] = 0.0; sums[1] = 0.0; sums[2] = 0.0;
    }
}

// ---------------- xb = bf16(feat/ls), xn = ||xb_row||^2 ----------------
__global__ void xb_kernel(const float* feat, const float* params, ushort* xb, float* xn) {
    int r = blockIdx.x;
    int l = threadIdx.x;  // 64 lanes
    float inv_ls = params[0];
    ushort h0 = f2bf(feat[r * DD + l] * inv_ls);
    ushort h1 = f2bf(feat[r * DD + 64 + l] * inv_ls);
    xb[r * DD + l] = h0;
    xb[r * DD + 64 + l] = h1;
    float v0 = bf2f(h0), v1 = bf2f(h1);
    float s = v0 * v0 + v1 * v1;
    for (int off = 32; off; off >>= 1) s += __shfl_xor(s, off);
    if (l == 0) xn[r] = s;
}

// ---------------- C0 = bf16(exp(-0.5 * sqdist)) via bf16 MFMA ----------------
__global__ __launch_bounds__(256) void c0_mfma_kernel(const ushort* xb, const float* xn,
                                                      ushort* C0b) {
    __shared__ float xr[128], xc[128];
    int t = threadIdx.x;
    int r0 = blockIdx.y * 128, c0 = blockIdx.x * 128;
    if (t < 128) xr[t] = xn[r0 + t];
    else xc[t - 128] = xn[c0 + (t - 128)];
    __syncthreads();

    int w = t >> 6, l = t & 63;
    int wr = w >> 1, wc = w & 1;
    int lr = l & 15;
    int lk = (l >> 4) * 8;
    const ushort* pa = xb + (size_t)(r0 + wr * 64 + lr) * DD + lk;
    const ushort* pb = xb + (size_t)(c0 + wc * 64 + lr) * DD + lk;

    v4f acc[4][4] = {};
    for (int ks = 0; ks < 4; ks++) {
        v8s a[4], b[4];
        for (int m = 0; m < 4; m++) a[m] = *(const v8s*)(pa + (size_t)m * 16 * DD + ks * 32);
        for (int n = 0; n < 4; n++) b[n] = *(const v8s*)(pb + (size_t)n * 16 * DD + ks * 32);
        for (int m = 0; m < 4; m++)
            for (int n = 0; n < 4; n++)
                acc[m][n] = __builtin_amdgcn_mfma_f32_16x16x32_bf16(a[m], b[n], acc[m][n], 0, 0, 0);
    }

    int rbase = wr * 64;
    int cbase = wc * 64;
    for (int m = 0; m < 4; m++) {
        for (int n = 0; n < 4; n++) {
            int ocol = cbase + n * 16 + lr;
            float xnc = xc[ocol];
            for (int j = 0; j < 4; j++) {
                int orow = rbase + m * 16 + (l >> 4) * 4 + j;
                float sq = xr[orow] + xnc - 2.f * acc[m][n][j];
                sq = fmaxf(sq, 0.f);
                C0b[(size_t)(r0 + orow) * NN + c0 + ocol] = f2bf(expf(-0.5f * sq));
            }
        }
    }
}

// ---------------- CSR extraction (block-masked), deterministic ----------------
__global__ void extract_kernel(const float* adj, int* nnzc, int* colsa) {
    __shared__ int sc[MAXNNZ];
    int b = blockIdx.x;        // a*NN + r
    int i = b >> 12;
    int r = b & (NN - 1);
    int lane = threadIdx.x;    // 64
    int base = (r < SS) ? 0 : SS;
    const float* arow = adj + ((size_t)i * NN + r) * NN + base;
    int cnt = 0;
    for (int it = 0; it < SS / 64; ++it) {
        int c = it * 64 + lane;
        float v = arow[c];
        unsigned long long m = __ballot(v != 0.f);
        if (v != 0.f) {
            int pos = cnt + __popcll(m & ((1ull << lane) - 1ull));
            if (pos < MAXNNZ) sc[pos] = c;  // relative col
        }
        cnt += __popcll(m);
    }
    if (cnt > MAXNNZ) cnt = MAXNNZ;
    __syncthreads();
    if (lane < cnt) colsa[(size_t)b * MAXNNZ + lane] = base + sc[lane];
    if (lane == 0) nnzc[b] = cnt;
}

// ---------------- merge both adjacencies into one byte-offset list per col ----------------
__global__ void merge_kernel(const int* nnzc, const int* colsa, ushort* moff, ushort* colinfo) {
    int c = blockIdx.x * 256 + threadIdx.x;
    if (c >= NN) return;
    int base = (c < SS) ? 0 : SS;
    int n0 = nnzc[c], n1 = nnzc[NN + c];
    int c0 = n0 < 8 ? n0 : 8;
    int c1 = n1 < 8 ? n1 : 8;
    ushort e[16];
    #pragma unroll
    for (int i = 0; i < 16; i++) e[i] = 8192;
    for (int i = 0; i < c0; i++)
        e[i] = (ushort)((colsa[(size_t)c * MAXNNZ + i] - base) * 4);
    for (int i = 0; i < c1; i++)
        e[c0 + i] = (ushort)((2056 + colsa[(size_t)(NN + c) * MAXNNZ + i] - base) * 4);
    uint4* mo = (uint4*)(moff + (size_t)c * 16);
    mo[0] = *(uint4*)&e[0];
    mo[1] = *(uint4*)&e[8];
    colinfo[c] = (ushort)((n0 > 8 || n1 > 8) ? 1 : 0);
}

// ---------------- diag of layer-1 K -> svec (double gather on bf16 C0) ----------------
__global__ void diag1_kernel(const ushort* C0b, const int* nnzc, const int* colsa,
                             const float* params, float* svec) {
    int t = threadIdx.x;
    int r = blockIdx.x * 4 + (t >> 6);
    int lane = t & 63;
    float c_add = params[1], w0 = params[2], w1 = params[3];
    float s = 0.f;
    for (int a = 0; a < 2; a++) {
        int b = a * NN + r;
        int cnt = nnzc[b];
        const int* crow = colsa + (size_t)b * MAXNNZ;
        int myk = crow[(lane < cnt) ? lane : 0];
        float wa = a ? w1 : w0;
        float acc = 0.f;
        for (int j = 0; j < cnt; j++) {
            int row = crow[j];
            if (lane < cnt) acc += bf2f(C0b[(size_t)row * NN + myk]);
        }
        s += wa * acc;
    }
    for (int off = 32; off; off >>= 1) s += __shfl_xor(s, off);
    if (lane == 0) {
        float d = c_add + s;
        svec[r] = sqrtf(fmaxf(d, 0.f)) + 1e-5f;
    }
}

// ---------------- fused conv, UPPER TRIANGLE only, batch-prefetch gather ----------------
// zones (blockIdx.x): 0: r=by (<S), h=0, cols c_rel>=by   (ss upper)
//                     1: r=by (<S), h=1, full span        (st)
//                     2: r=S+by,    h=1, cols c_rel>=by   (tt upper)
template <int MODE>
__global__ __launch_bounds__(256, 8) void conv_kernel(const ushort* __restrict__ Kb,
                                                      const int* __restrict__ nnzc,
                                                      const int* __restrict__ colsa,
                                                      const uint4* __restrict__ moffq,
                                                      const ushort* __restrict__ colinfo,
                                                      const float* __restrict__ params,
                                                      const float* __restrict__ svec,
                                                      void* __restrict__ Kout_,
                                                      double* __restrict__ sums) {
    __shared__ float rs[4112];
    __shared__ double red[256];
    int zone = blockIdx.x;
    int by = blockIdx.y;
    int r = (zone == 2) ? SS + by : by;
    int h = (zone >= 1) ? 1 : 0;
    int cstart = (zone == 1) ? 0 : by;
    int cbase = h * HB;
    int t = threadIdx.x;
    float c_add = params[1], w0 = params[2], w1 = params[3];

    // ---- rowsum (sequential streams — R9 ablation: ILP here is irrelevant) ----
    {
        float acc0[8], acc1[8];
        #pragma unroll
        for (int e = 0; e < 8; e++) { acc0[e] = 0.f; acc1[e] = 0.f; }
        int cnt0 = nnzc[r], cnt1 = nnzc[NN + r];
        const int* crow0 = colsa + (size_t)r * MAXNNZ;
        const int* crow1 = colsa + (size_t)(NN + r) * MAXNNZ;
        for (int j = 0; j < cnt0; j++) {
            uint4 v = *(const uint4*)(Kb + (size_t)crow0[j] * NN + cbase + t * 8);
            acc0[0] += blo(v.x); acc0[1] += bhi(v.x);
            acc0[2] += blo(v.y); acc0[3] += bhi(v.y);
            acc0[4] += blo(v.z); acc0[5] += bhi(v.z);
            acc0[6] += blo(v.w); acc0[7] += bhi(v.w);
        }
        for (int j = 0; j < cnt1; j++) {
            uint4 v = *(const uint4*)(Kb + (size_t)crow1[j] * NN + cbase + t * 8);
            acc1[0] += blo(v.x); acc1[1] += bhi(v.x);
            acc1[2] += blo(v.y); acc1[3] += bhi(v.y);
            acc1[4] += blo(v.z); acc1[5] += bhi(v.z);
            acc1[6] += blo(v.w); acc1[7] += bhi(v.w);
        }
        *(float4*)&rs[8 * t]            = {acc0[0]*w0, acc0[1]*w0, acc0[2]*w0, acc0[3]*w0};
        *(float4*)&rs[8 * t + 4]        = {acc0[4]*w0, acc0[5]*w0, acc0[6]*w0, acc0[7]*w0};
        *(float4*)&rs[2056 + 8 * t]     = {acc1[0]*w1, acc1[1]*w1, acc1[2]*w1, acc1[3]*w1};
        *(float4*)&rs[2056 + 8 * t + 4] = {acc1[4]*w1, acc1[5]*w1, acc1[6]*w1, acc1[7]*w1};
        if (t < 8) { rs[2048 + t] = 0.f; rs[4104 + t] = 0.f; }
    }
    __syncthreads();

    // ---- gather: macro-batches of 4 cols; prefetch ALL offsets, then pure-LDS chains ----
    float sr = (MODE == 0) ? svec[r] : 0.f;
    double dsum = 0.0;
    ushort* out_b = (ushort*)Kout_;
    float* out_f = (float*)Kout_;
    const char* rsb = (const char*)rs;
    int n_u = (HB - cstart + 255) >> 8;  // uniform slot count (1..8)

    #pragma unroll
    for (int mb = 0; mb < 2; mb++) {
        if (mb * 4 >= n_u) break;  // uniform branch
        // --- phase 1: prefetch offsets + colinfo for 4 cols (no LDS ops) ---
        int cols[4];
        uint4 mo[4][2];
        ushort ci[4];
        #pragma unroll
        for (int q = 0; q < 4; q++) {
            int u = mb * 4 + q;
            int c_rel = cstart + t + 256 * u;
            bool act = (u < n_u) && (c_rel < HB);
            int col = cbase + (act ? c_rel : 0);
            const uint4* mop = moffq + (size_t)col * 2;
            mo[q][0] = mop[0];
            mo[q][1] = mop[1];
            ci[q] = colinfo[col];
            cols[q] = act ? col : -1;
        }
        // --- phase 2: 4 independent pure-LDS accumulation chains ---
        float ac[4];
        #pragma unroll
        for (int q = 0; q < 4; q++) {
            uint4 m0 = mo[q][0], m1 = mo[q][1];
            float s0 = *(const float*)(rsb + (m0.x & 0xffffu))
                     + *(const float*)(rsb + (m0.x >> 16));
            float s1 = *(const float*)(rsb + (m0.y & 0xffffu))
                     + *(const float*)(rsb + (m0.y >> 16));
            float s2 = *(const float*)(rsb + (m0.z & 0xffffu))
                     + *(const float*)(rsb + (m0.z >> 16));
            float s3 = *(const float*)(rsb + (m0.w & 0xffffu))
                     + *(const float*)(rsb + (m0.w >> 16));
            float s4 = *(const float*)(rsb + (m1.x & 0xffffu))
                     + *(const float*)(rsb + (m1.x >> 16));
            float s5 = *(const float*)(rsb + (m1.y & 0xffffu))
                     + *(const float*)(rsb + (m1.y >> 16));
            float s6 = *(const float*)(rsb + (m1.z & 0xffffu))
                     + *(const float*)(rsb + (m1.z >> 16));
            float s7 = *(const float*)(rsb + (m1.w & 0xffffu))
                     + *(const float*)(rsb + (m1.w >> 16));
            ac[q] = ((s0 + s1) + (s2 + s3)) + ((s4 + s5) + (s6 + s7));
        }
        // --- phase 3: epilogues ---
        #pragma unroll
        for (int q = 0; q < 4; q++) {
            int col = cols[q];
            if (col < 0) continue;
            float acc = ac[q];
            if (ci[q] & 1) {  // rare overflow (>8 nnz in either adjacency)
                for (int a = 0; a < 2; a++) {
                    int b = a * NN + col;
                    int cnt = nnzc[b];
                    if (cnt > 8) {
                        const int* cp = colsa + (size_t)b * MAXNNZ;
                        for (int k = 8; k < cnt; k++)
                            acc += rs[(cp[k] & (HB - 1)) + (a ? 2056 : 0)];
                    }
                }
            }
            float kv = c_add + acc;
            if (MODE == 0) {
                const float PIF = 3.14159265358979323846f;
                const float INV2PI = 0.15915494309189535f;
                float pp = sr * svec[col];
                float cc = kv / pp;
                cc = fminf(fmaxf(cc, -1.f + 1e-6f), 1.f - 1e-6f);
                float th = acosf(cc);
                float sth = sqrtf(fmaxf(1.f - cc * cc, 0.f));
                kv = INV2PI * (sth + (PIF - th) * cc) * pp;
                out_b[(size_t)r * NN + col] = f2bf(kv);
            } else {
                out_f[(size_t)r * NN + col] = kv;  // unscaled upper
                int c_rel = col - cbase;
                if (zone == 1) dsum += (double)kv;
                else dsum += (c_rel == by) ? (double)kv : 2.0 * (double)kv;
            }
        }
    }

    if (MODE == 1) {
        red[t] = dsum;
        __syncthreads();
        for (int off = 128; off; off >>= 1) {
            if (t < off) red[t] += red[t + off];
            __syncthreads();
        }
        if (t == 0) atomicAdd(&sums[zone], red[0]);  // zone0->ss, zone1->st, zone2->tt
    }
}

// ---------------- mirror bf16 upper -> lower (tiled LDS transpose) ----------------
__global__ __launch_bounds__(256) void mirror_kernel(ushort* Kb) {
    int bi = blockIdx.x;
    int bj = blockIdx.y;
    if (bj < bi) return;
    __shared__ ushort lds[64][66];
    int R0 = bi * 64, C0 = bj * 64;
    int t = threadIdx.x;
    #pragma unroll
    for (int k = 0; k < 16; k++) {
        int lin = k * 256 + t;
        int row = lin >> 6, col = lin & 63;
        lds[row][col] = Kb[(size_t)(R0 + row) * NN + C0 + col];
    }
    __syncthreads();
    if (bj > bi) {
        #pragma unroll
        for (int k = 0; k < 16; k++) {
            int lin = k * 256 + t;
            int row = lin >> 6, col = lin & 63;
            Kb[(size_t)(C0 + row) * NN + R0 + col] = lds[col][row];
        }
    } else {
        #pragma unroll
        for (int k = 0; k < 16; k++) {
            int lin = k * 256 + t;
            int row = lin >> 6, col = lin & 63;
            if (row > col) Kb[(size_t)(R0 + row) * NN + R0 + col] = lds[col][row];
        }
    }
}

// ---------------- finalize: scale upper in place + write scaled transpose to lower ----------------
__global__ __launch_bounds__(256) void finalize_kernel(float* out, const double* sums) {
    int bi = blockIdx.x;
    int bj = blockIdx.y;
    if (bj < bi) return;
    __shared__ float lds[64][65];
    const double inv = 1.0 / (2048.0 * 2048.0);
    float mss = (float)(sums[0] * inv);
    float mst = (float)(sums[1] * inv);
    float mtt = (float)(sums[2] * inv);
    int R0 = bi * 64, C0 = bj * 64;
    float m = (R0 < SS) ? (C0 < SS ? mss : mst) : (C0 < SS ? mst : mtt);
    int t = threadIdx.x;
    #pragma unroll
    for (int k = 0; k < 16; k++) {
        int lin = k * 256 + t;
        int row = lin >> 6, col = lin & 63;
        lds[row][col] = out[(size_t)(R0 + row) * NN + C0 + col];
    }
    __syncthreads();
    if (bj > bi) {
        #pragma unroll
        for (int k = 0; k < 16; k++) {
            int lin = k * 256 + t;
            int row = lin >> 6, col = lin & 63;
            out[(size_t)(R0 + row) * NN + C0 + col] = m * lds[row][col];
            out[(size_t)(C0 + row) * NN + R0 + col] = m * lds[col][row];
        }
    } else {
        #pragma unroll
        for (int k = 0; k < 16; k++) {
            int lin = k * 256 + t;
            int row = lin >> 6, col = lin & 63;
            float v = (row <= col) ? lds[row][col] : lds[col][row];
            out[(size_t)(R0 + row) * NN + R0 + col] = m * v;
        }
    }
}

extern "C" void kernel_launch(void* const* d_in, const int* in_sizes, int n_in,
                              void* d_out, int out_size, void* d_ws, size_t ws_size,
                              hipStream_t stream) {
    const float* feat = (const float*)d_in[0];
    const float* adj  = (const float*)d_in[1];
    const float* rls  = (const float*)d_in[2];
    const float* rvw  = (const float*)d_in[3];
    const float* rsw  = (const float*)d_in[4];
    const float* rsb  = (const float*)d_in[5];
    const float* rsa  = (const float*)d_in[6];
    const float* rta  = (const float*)d_in[7];
    float* out = (float*)d_out;

    const size_t PNN = (size_t)NN * NN;
    char* p = (char*)d_ws;
    auto alloc = [&](size_t bytes) {
        char* r = p;
        p += (bytes + 255) & ~(size_t)255;
        return r;
    };
    float*  params   = (float*)alloc(64);
    double* sums     = (double*)alloc(64);
    float*  xn       = (float*)alloc((size_t)NN * 4);
    float*  svec     = (float*)alloc((size_t)NN * 4);
    int*    nnzc     = (int*)alloc((size_t)2 * NN * 4);
    int*    colsa    = (int*)alloc((size_t)2 * NN * MAXNNZ * 4);
    ushort* moff     = (ushort*)alloc((size_t)NN * 16 * 2);
    ushort* colinfo  = (ushort*)alloc((size_t)NN * 2);
    ushort* xb       = (ushort*)alloc((size_t)NN * DD * 2);
    ushort* cb0      = (ushort*)alloc(PNN * 2);   // 32 MiB bf16 C0
    ushort* kb1      = (ushort*)alloc(PNN * 2);   // 32 MiB bf16 relu(K1)

    params_kernel<<<1, 64, 0, stream>>>(rls, rvw, rsw, rsb, rsa, rta, params, sums);
    xb_kernel<<<NN, 64, 0, stream>>>(feat, params, xb, xn);
    c0_mfma_kernel<<<dim3(NN / 128, NN / 128), 256, 0, stream>>>(xb, xn, cb0);
    extract_kernel<<<NADJ * NN, 64, 0, stream>>>(adj, nnzc, colsa);
    merge_kernel<<<(NN + 255) / 256, 256, 0, stream>>>(nnzc, colsa, moff, colinfo);

    // svec = sqrt(diag(layer1 K)) from double-gather on C0
    diag1_kernel<<<NN / 4, 256, 0, stream>>>(cb0, nnzc, colsa, params, svec);

    // layer 1 (upper only): C0 (bf16) -> relu_cov(K1) (bf16), then mirror to full
    conv_kernel<0><<<dim3(3, HB), 256, 0, stream>>>(cb0, nnzc, colsa, (const uint4*)moff,
                                                    colinfo, params, svec, kb1, sums);
    mirror_kernel<<<dim3(64, 64), 256, 0, stream>>>(kb1);

    // layer 2 (upper only): K1 (bf16) -> unscaled K2 (fp32) in d_out + block sums
    conv_kernel<1><<<dim3(3, HB), 256, 0, stream>>>(kb1, nnzc, colsa, (const uint4*)moff,
                                                    colinfo, params, svec, out, sums);

    // scale by block means + fill lower triangle (transpose)
    finalize_kernel<<<dim3(64, 64), 256, 0, stream>>>(out, sums);
}

// Round 13
// 263.991 us; speedup vs baseline: 1.2280x; 1.1388x over previous
//
#include <hip/hip_runtime.h>
#include <math.h>

#define NN 4096
#define SS 2048
#define DD 128
#define NADJ 2
#define MAXNNZ 64
#define HB 2048   // half-block width (cols per conv block)

typedef short v8s __attribute__((ext_vector_type(8)));
typedef float v4f __attribute__((ext_vector_type(4)));

__device__ __forceinline__ float softplusf(float x) {
    if (x > 20.f) return x;
    if (x < -20.f) return expf(x);
    return log1pf(expf(x));
}

__device__ __forceinline__ ushort f2bf(float f) {
    unsigned int u = __float_as_uint(f);
    unsigned int r = (u + 0x7fff + ((u >> 16) & 1)) >> 16;  // RNE
    return (ushort)r;
}
__device__ __forceinline__ float bf2f(ushort h) {
    return __uint_as_float(((unsigned int)h) << 16);
}
__device__ __forceinline__ float blo(unsigned int u) { return __uint_as_float(u << 16); }
__device__ __forceinline__ float bhi(unsigned int u) { return __uint_as_float(u & 0xffff0000u); }

// ---------------- params + zero sums ----------------
__global__ void params_kernel(const float* rls, const float* rvw, const float* rsw,
                              const float* rsb, const float* rsa, const float* rta,
                              float* params, double* sums) {
    if (threadIdx.x == 0) {
        float ls = softplusf(rls[0]);
        float vw = softplusf(rvw[0]);
        float sw = softplusf(rsw[0]);
        float sb = softplusf(rsb[0]);
        float a0 = softplusf(rsa[0]) * softplusf(rta[0]);
        float a1 = softplusf(rsa[1]) * softplusf(rta[1]);
        float vw2 = vw * vw, sw2 = sw * sw, sb2 = sb * sb;
        params[0] = 1.f / ls;
        params[1] = vw2 * sb2 * (a0 + a1);  // c_add
        params[2] = vw2 * sw2 * a0;         // w0
        params[3] = vw2 * sw2 * a1;         // w1
        sums[0] = 0.0; sums[1] = 0.0; sums[2] = 0.0;
    }
}

// ---------------- xb = bf16(feat/ls), xn = ||xb_row||^2 ----------------
__global__ void xb_kernel(const float* feat, const float* params, ushort* xb, float* xn) {
    int r = blockIdx.x;
    int l = threadIdx.x;  // 64 lanes
    float inv_ls = params[0];
    ushort h0 = f2bf(feat[r * DD + l] * inv_ls);
    ushort h1 = f2bf(feat[r * DD + 64 + l] * inv_ls);
    xb[r * DD + l] = h0;
    xb[r * DD + 64 + l] = h1;
    float v0 = bf2f(h0), v1 = bf2f(h1);
    float s = v0 * v0 + v1 * v1;
    for (int off = 32; off; off >>= 1) s += __shfl_xor(s, off);
    if (l == 0) xn[r] = s;
}

// ---------------- C0 = bf16(exp(-0.5 * sqdist)) via bf16 MFMA ----------------
__global__ __launch_bounds__(256) void c0_mfma_kernel(const ushort* xb, const float* xn,
                                                      ushort* C0b) {
    __shared__ float xr[128], xc[128];
    int t = threadIdx.x;
    int r0 = blockIdx.y * 128, c0 = blockIdx.x * 128;
    if (t < 128) xr[t] = xn[r0 + t];
    else xc[t - 128] = xn[c0 + (t - 128)];
    __syncthreads();

    int w = t >> 6, l = t & 63;
    int wr = w >> 1, wc = w & 1;
    int lr = l & 15;
    int lk = (l >> 4) * 8;
    const ushort* pa = xb + (size_t)(r0 + wr * 64 + lr) * DD + lk;
    const ushort* pb = xb + (size_t)(c0 + wc * 64 + lr) * DD + lk;

    v4f acc[4][4] = {};
    for (int ks = 0; ks < 4; ks++) {
        v8s a[4], b[4];
        for (int m = 0; m < 4; m++) a[m] = *(const v8s*)(pa + (size_t)m * 16 * DD + ks * 32);
        for (int n = 0; n < 4; n++) b[n] = *(const v8s*)(pb + (size_t)n * 16 * DD + ks * 32);
        for (int m = 0; m < 4; m++)
            for (int n = 0; n < 4; n++)
                acc[m][n] = __builtin_amdgcn_mfma_f32_16x16x32_bf16(a[m], b[n], acc[m][n], 0, 0, 0);
    }

    int rbase = wr * 64;
    int cbase = wc * 64;
    for (int m = 0; m < 4; m++) {
        for (int n = 0; n < 4; n++) {
            int ocol = cbase + n * 16 + lr;
            float xnc = xc[ocol];
            for (int j = 0; j < 4; j++) {
                int orow = rbase + m * 16 + (l >> 4) * 4 + j;
                float sq = xr[orow] + xnc - 2.f * acc[m][n][j];
                sq = fmaxf(sq, 0.f);
                C0b[(size_t)(r0 + orow) * NN + c0 + ocol] = f2bf(expf(-0.5f * sq));
            }
        }
    }
}

// ---------------- CSR extraction (block-masked), deterministic ----------------
__global__ void extract_kernel(const float* adj, int* nnzc, int* colsa) {
    __shared__ int sc[MAXNNZ];
    int b = blockIdx.x;        // a*NN + r
    int i = b >> 12;
    int r = b & (NN - 1);
    int lane = threadIdx.x;    // 64
    int base = (r < SS) ? 0 : SS;
    const float* arow = adj + ((size_t)i * NN + r) * NN + base;
    int cnt = 0;
    for (int it = 0; it < SS / 64; ++it) {
        int c = it * 64 + lane;
        float v = arow[c];
        unsigned long long m = __ballot(v != 0.f);
        if (v != 0.f) {
            int pos = cnt + __popcll(m & ((1ull << lane) - 1ull));
            if (pos < MAXNNZ) sc[pos] = c;  // relative col
        }
        cnt += __popcll(m);
    }
    if (cnt > MAXNNZ) cnt = MAXNNZ;
    __syncthreads();
    if (lane < cnt) colsa[(size_t)b * MAXNNZ + lane] = base + sc[lane];
    if (lane == 0) nnzc[b] = cnt;
}

// ---------------- merge both adjacencies into one byte-offset list per col ----------------
__global__ void merge_kernel(const int* nnzc, const int* colsa, ushort* moff, ushort* colinfo) {
    int c = blockIdx.x * 256 + threadIdx.x;
    if (c >= NN) return;
    int base = (c < SS) ? 0 : SS;
    int n0 = nnzc[c], n1 = nnzc[NN + c];
    int c0 = n0 < 8 ? n0 : 8;
    int c1 = n1 < 8 ? n1 : 8;
    ushort e[16];
    #pragma unroll
    for (int i = 0; i < 16; i++) e[i] = 8192;
    for (int i = 0; i < c0; i++)
        e[i] = (ushort)((colsa[(size_t)c * MAXNNZ + i] - base) * 4);
    for (int i = 0; i < c1; i++)
        e[c0 + i] = (ushort)((2056 + colsa[(size_t)(NN + c) * MAXNNZ + i] - base) * 4);
    uint4* mo = (uint4*)(moff + (size_t)c * 16);
    mo[0] = *(uint4*)&e[0];
    mo[1] = *(uint4*)&e[8];
    colinfo[c] = (ushort)((n0 > 8 || n1 > 8) ? 1 : 0);
}

// ---------------- diag of layer-1 K -> svec (double gather on bf16 C0) ----------------
__global__ void diag1_kernel(const ushort* C0b, const int* nnzc, const int* colsa,
                             const float* params, float* svec) {
    int t = threadIdx.x;
    int r = blockIdx.x * 4 + (t >> 6);
    int lane = t & 63;
    float c_add = params[1], w0 = params[2], w1 = params[3];
    float s = 0.f;
    for (int a = 0; a < 2; a++) {
        int b = a * NN + r;
        int cnt = nnzc[b];
        const int* crow = colsa + (size_t)b * MAXNNZ;
        int myk = crow[(lane < cnt) ? lane : 0];
        float wa = a ? w1 : w0;
        float acc = 0.f;
        for (int j = 0; j < cnt; j++) {
            int row = crow[j];
            if (lane < cnt) acc += bf2f(C0b[(size_t)row * NN + myk]);
        }
        s += wa * acc;
    }
    for (int off = 32; off; off >>= 1) s += __shfl_xor(s, off);
    if (lane == 0) {
        float d = c_add + s;
        svec[r] = sqrtf(fmaxf(d, 0.f)) + 1e-5f;
    }
}

// ---------------- fused conv, UPPER TRIANGLE only ----------------
// launch_bounds(256,4): 128 VGPR/wave -> full rowsum preload + 4-col gather prefetch.
// SAFETY: preload clamp must be literal 0 (colsa entries beyond cnt are GARBAGE,
// including entry 0 when cnt==0 — caused R12's fault).
// zones (blockIdx.x): 0: r=by (<S), h=0, cols c_rel>=by   (ss upper)
//                     1: r=by (<S), h=1, full span        (st)
//                     2: r=S+by,    h=1, cols c_rel>=by   (tt upper)
template <int MODE>
__global__ __launch_bounds__(256, 4) void conv_kernel(const ushort* __restrict__ Kb,
                                                      const int* __restrict__ nnzc,
                                                      const int* __restrict__ colsa,
                                                      const uint4* __restrict__ moffq,
                                                      const ushort* __restrict__ colinfo,
                                                      const float* __restrict__ params,
                                                      const float* __restrict__ svec,
                                                      void* __restrict__ Kout_,
                                                      double* __restrict__ sums) {
    __shared__ float rs[4112];
    __shared__ double red[256];
    int zone = blockIdx.x;
    int by = blockIdx.y;
    int r = (zone == 2) ? SS + by : by;
    int h = (zone >= 1) ? 1 : 0;
    int cstart = (zone == 1) ? 0 : by;
    int cbase = h * HB;
    int t = threadIdx.x;
    float c_add = params[1], w0 = params[2], w1 = params[3];

    // ---- rowsum: preload ALL 16 neighbor rows into registers (max MLP) ----
    {
        int cnt0 = nnzc[r], cnt1 = nnzc[NN + r];
        const int* crow0 = colsa + (size_t)r * MAXNNZ;
        const int* crow1 = colsa + (size_t)(NN + r) * MAXNNZ;
        int4 ia0 = *(const int4*)crow0;
        int4 ib0 = *(const int4*)(crow0 + 4);
        int4 ia1 = *(const int4*)crow1;
        int4 ib1 = *(const int4*)(crow1 + 4);
        int id0[8] = {ia0.x, ia0.y, ia0.z, ia0.w, ib0.x, ib0.y, ib0.z, ib0.w};
        int id1[8] = {ia1.x, ia1.y, ia1.z, ia1.w, ib1.x, ib1.y, ib1.z, ib1.w};

        uint4 v0[8], v1[8];
        #pragma unroll
        for (int j = 0; j < 8; j++) {
            int row0 = (j < cnt0) ? id0[j] : 0;   // literal 0: always-valid row
            int row1 = (j < cnt1) ? id1[j] : 0;
            v0[j] = *(const uint4*)(Kb + (size_t)row0 * NN + cbase + t * 8);
            v1[j] = *(const uint4*)(Kb + (size_t)row1 * NN + cbase + t * 8);
        }

        float acc0[8], acc1[8];
        #pragma unroll
        for (int e = 0; e < 8; e++) { acc0[e] = 0.f; acc1[e] = 0.f; }
        #pragma unroll
        for (int j = 0; j < 8; j++) {
            if (j < cnt0) {
                uint4 v = v0[j];
                acc0[0] += blo(v.x); acc0[1] += bhi(v.x);
                acc0[2] += blo(v.y); acc0[3] += bhi(v.y);
                acc0[4] += blo(v.z); acc0[5] += bhi(v.z);
                acc0[6] += blo(v.w); acc0[7] += bhi(v.w);
            }
            if (j < cnt1) {
                uint4 v = v1[j];
                acc1[0] += blo(v.x); acc1[1] += bhi(v.x);
                acc1[2] += blo(v.y); acc1[3] += bhi(v.y);
                acc1[4] += blo(v.z); acc1[5] += bhi(v.z);
                acc1[6] += blo(v.w); acc1[7] += bhi(v.w);
            }
        }
        for (int j = 8; j < cnt0; j++) {  // rare tail
            uint4 v = *(const uint4*)(Kb + (size_t)crow0[j] * NN + cbase + t * 8);
            acc0[0] += blo(v.x); acc0[1] += bhi(v.x);
            acc0[2] += blo(v.y); acc0[3] += bhi(v.y);
            acc0[4] += blo(v.z); acc0[5] += bhi(v.z);
            acc0[6] += blo(v.w); acc0[7] += bhi(v.w);
        }
        for (int j = 8; j < cnt1; j++) {
            uint4 v = *(const uint4*)(Kb + (size_t)crow1[j] * NN + cbase + t * 8);
            acc1[0] += blo(v.x); acc1[1] += bhi(v.x);
            acc1[2] += blo(v.y); acc1[3] += bhi(v.y);
            acc1[4] += blo(v.z); acc1[5] += bhi(v.z);
            acc1[6] += blo(v.w); acc1[7] += bhi(v.w);
        }
        *(float4*)&rs[8 * t]            = {acc0[0]*w0, acc0[1]*w0, acc0[2]*w0, acc0[3]*w0};
        *(float4*)&rs[8 * t + 4]        = {acc0[4]*w0, acc0[5]*w0, acc0[6]*w0, acc0[7]*w0};
        *(float4*)&rs[2056 + 8 * t]     = {acc1[0]*w1, acc1[1]*w1, acc1[2]*w1, acc1[3]*w1};
        *(float4*)&rs[2056 + 8 * t + 4] = {acc1[4]*w1, acc1[5]*w1, acc1[6]*w1, acc1[7]*w1};
        if (t < 8) { rs[2048 + t] = 0.f; rs[4104 + t] = 0.f; }
    }
    __syncthreads();

    // ---- gather: macro-batches of 4 cols; prefetch offsets, then pure-LDS chains ----
    float sr = (MODE == 0) ? svec[r] : 0.f;
    double dsum = 0.0;
    ushort* out_b = (ushort*)Kout_;
    float* out_f = (float*)Kout_;
    const char* rsb = (const char*)rs;
    int n_u = (HB - cstart + 255) >> 8;  // uniform slot count (1..8)

    #pragma unroll
    for (int mb = 0; mb < 2; mb++) {
        if (mb * 4 >= n_u) break;  // uniform branch
        int cols[4];
        uint4 mo[4][2];
        ushort ci[4];
        #pragma unroll
        for (int q = 0; q < 4; q++) {
            int u = mb * 4 + q;
            int c_rel = cstart + t + 256 * u;
            bool act = (u < n_u) && (c_rel < HB);
            int col = cbase + (act ? c_rel : 0);
            const uint4* mop = moffq + (size_t)col * 2;
            mo[q][0] = mop[0];
            mo[q][1] = mop[1];
            ci[q] = colinfo[col];
            cols[q] = act ? col : -1;
        }
        float ac[4];
        #pragma unroll
        for (int q = 0; q < 4; q++) {
            uint4 m0 = mo[q][0], m1 = mo[q][1];
            float s0 = *(const float*)(rsb + (m0.x & 0xffffu))
                     + *(const float*)(rsb + (m0.x >> 16));
            float s1 = *(const float*)(rsb + (m0.y & 0xffffu))
                     + *(const float*)(rsb + (m0.y >> 16));
            float s2 = *(const float*)(rsb + (m0.z & 0xffffu))
                     + *(const float*)(rsb + (m0.z >> 16));
            float s3 = *(const float*)(rsb + (m0.w & 0xffffu))
                     + *(const float*)(rsb + (m0.w >> 16));
            float s4 = *(const float*)(rsb + (m1.x & 0xffffu))
                     + *(const float*)(rsb + (m1.x >> 16));
            float s5 = *(const float*)(rsb + (m1.y & 0xffffu))
                     + *(const float*)(rsb + (m1.y >> 16));
            float s6 = *(const float*)(rsb + (m1.z & 0xffffu))
                     + *(const float*)(rsb + (m1.z >> 16));
            float s7 = *(const float*)(rsb + (m1.w & 0xffffu))
                     + *(const float*)(rsb + (m1.w >> 16));
            ac[q] = ((s0 + s1) + (s2 + s3)) + ((s4 + s5) + (s6 + s7));
        }
        #pragma unroll
        for (int q = 0; q < 4; q++) {
            int col = cols[q];
            if (col < 0) continue;
            float acc = ac[q];
            if (ci[q] & 1) {  // rare overflow (>8 nnz in either adjacency)
                for (int a = 0; a < 2; a++) {
                    int b = a * NN + col;
                    int cnt = nnzc[b];
                    if (cnt > 8) {
                        const int* cp = colsa + (size_t)b * MAXNNZ;
                        for (int k = 8; k < cnt; k++)
                            acc += rs[(cp[k] & (HB - 1)) + (a ? 2056 : 0)];
                    }
                }
            }
            float kv = c_add + acc;
            if (MODE == 0) {
                const float PIF = 3.14159265358979323846f;
                const float INV2PI = 0.15915494309189535f;
                float pp = sr * svec[col];
                float cc = kv / pp;
                cc = fminf(fmaxf(cc, -1.f + 1e-6f), 1.f - 1e-6f);
                float th = acosf(cc);
                float sth = sqrtf(fmaxf(1.f - cc * cc, 0.f));
                kv = INV2PI * (sth + (PIF - th) * cc) * pp;
                out_b[(size_t)r * NN + col] = f2bf(kv);
            } else {
                out_f[(size_t)r * NN + col] = kv;  // unscaled upper
                int c_rel = col - cbase;
                if (zone == 1) dsum += (double)kv;
                else dsum += (c_rel == by) ? (double)kv : 2.0 * (double)kv;
            }
        }
    }

    if (MODE == 1) {
        red[t] = dsum;
        __syncthreads();
        for (int off = 128; off; off >>= 1) {
            if (t < off) red[t] += red[t + off];
            __syncthreads();
        }
        if (t == 0) atomicAdd(&sums[zone], red[0]);  // zone0->ss, zone1->st, zone2->tt
    }
}

// ---------------- mirror bf16 upper -> lower (tiled LDS transpose) ----------------
__global__ __launch_bounds__(256) void mirror_kernel(ushort* Kb) {
    int bi = blockIdx.x;
    int bj = blockIdx.y;
    if (bj < bi) return;
    __shared__ ushort lds[64][66];
    int R0 = bi * 64, C0 = bj * 64;
    int t = threadIdx.x;
    #pragma unroll
    for (int k = 0; k < 16; k++) {
        int lin = k * 256 + t;
        int row = lin >> 6, col = lin & 63;
        lds[row][col] = Kb[(size_t)(R0 + row) * NN + C0 + col];
    }
    __syncthreads();
    if (bj > bi) {
        #pragma unroll
        for (int k = 0; k < 16; k++) {
            int lin = k * 256 + t;
            int row = lin >> 6, col = lin & 63;
            Kb[(size_t)(C0 + row) * NN + R0 + col] = lds[col][row];
        }
    } else {
        #pragma unroll
        for (int k = 0; k < 16; k++) {
            int lin = k * 256 + t;
            int row = lin >> 6, col = lin & 63;
            if (row > col) Kb[(size_t)(R0 + row) * NN + R0 + col] = lds[col][row];
        }
    }
}

// ---------------- finalize: scale upper in place + write scaled transpose to lower ----------------
__global__ __launch_bounds__(256) void finalize_kernel(float* out, const double* sums) {
    int bi = blockIdx.x;
    int bj = blockIdx.y;
    if (bj < bi) return;
    __shared__ float lds[64][65];
    const double inv = 1.0 / (2048.0 * 2048.0);
    float mss = (float)(sums[0] * inv);
    float mst = (float)(sums[1] * inv);
    float mtt = (float)(sums[2] * inv);
    int R0 = bi * 64, C0 = bj * 64;
    float m = (R0 < SS) ? (C0 < SS ? mss : mst) : (C0 < SS ? mst : mtt);
    int t = threadIdx.x;
    #pragma unroll
    for (int k = 0; k < 16; k++) {
        int lin = k * 256 + t;
        int row = lin >> 6, col = lin & 63;
        lds[row][col] = out[(size_t)(R0 + row) * NN + C0 + col];
    }
    __syncthreads();
    if (bj > bi) {
        #pragma unroll
        for (int k = 0; k < 16; k++) {
            int lin = k * 256 + t;
            int row = lin >> 6, col = lin & 63;
            out[(size_t)(R0 + row) * NN + C0 + col] = m * lds[row][col];
            out[(size_t)(C0 + row) * NN + R0 + col] = m * lds[col][row];
        }
    } else {
        #pragma unroll
        for (int k = 0; k < 16; k++) {
            int lin = k * 256 + t;
            int row = lin >> 6, col = lin & 63;
            float v = (row <= col) ? lds[row][col] : lds[col][row];
            out[(size_t)(R0 + row) * NN + R0 + col] = m * v;
        }
    }
}

extern "C" void kernel_launch(void* const* d_in, const int* in_sizes, int n_in,
                              void* d_out, int out_size, void* d_ws, size_t ws_size,
                              hipStream_t stream) {
    const float* feat = (const float*)d_in[0];
    const float* adj  = (const float*)d_in[1];
    const float* rls  = (const float*)d_in[2];
    const float* rvw  = (const float*)d_in[3];
    const float* rsw  = (const float*)d_in[4];
    const float* rsb  = (const float*)d_in[5];
    const float* rsa  = (const float*)d_in[6];
    const float* rta  = (const float*)d_in[7];
    float* out = (float*)d_out;

    const size_t PNN = (size_t)NN * NN;
    char* p = (char*)d_ws;
    auto alloc = [&](size_t bytes) {
        char* r = p;
        p += (bytes + 255) & ~(size_t)255;
        return r;
    };
    float*  params   = (float*)alloc(64);
    double* sums     = (double*)alloc(64);
    float*  xn       = (float*)alloc((size_t)NN * 4);
    float*  svec     = (float*)alloc((size_t)NN * 4);
    int*    nnzc     = (int*)alloc((size_t)2 * NN * 4);
    int*    colsa    = (int*)alloc((size_t)2 * NN * MAXNNZ * 4);
    ushort* moff     = (ushort*)alloc((size_t)NN * 16 * 2);
    ushort* colinfo  = (ushort*)alloc((size_t)NN * 2);
    ushort* xb       = (ushort*)alloc((size_t)NN * DD * 2);
    ushort* cb0      = (ushort*)alloc(PNN * 2);   // 32 MiB bf16 C0
    ushort* kb1      = (ushort*)alloc(PNN * 2);   // 32 MiB bf16 relu(K1)

    params_kernel<<<1, 64, 0, stream>>>(rls, rvw, rsw, rsb, rsa, rta, params, sums);
    xb_kernel<<<NN, 64, 0, stream>>>(feat, params, xb, xn);
    c0_mfma_kernel<<<dim3(NN / 128, NN / 128), 256, 0, stream>>>(xb, xn, cb0);
    extract_kernel<<<NADJ * NN, 64, 0, stream>>>(adj, nnzc, colsa);
    merge_kernel<<<(NN + 255) / 256, 256, 0, stream>>>(nnzc, colsa, moff, colinfo);

    // svec = sqrt(diag(layer1 K)) from double-gather on C0
    diag1_kernel<<<NN / 4, 256, 0, stream>>>(cb0, nnzc, colsa, params, svec);

    // layer 1 (upper only): C0 (bf16) -> relu_cov(K1) (bf16), then mirror to full
    conv_kernel<0><<<dim3(3, HB), 256, 0, stream>>>(cb0, nnzc, colsa, (const uint4*)moff,
                                                    colinfo, params, svec, kb1, sums);
    mirror_kernel<<<dim3(64, 64), 256, 0, stream>>>(kb1);

    // layer 2 (upper only): K1 (bf16) -> unscaled K2 (fp32) in d_out + block sums
    conv_kernel<1><<<dim3(3, HB), 256, 0, stream>>>(kb1, nnzc, colsa, (const uint4*)moff,
                                                    colinfo, params, svec, out, sums);

    // scale by block means + fill lower triangle (transpose)
    finalize_kernel<<<dim3(64, 64), 256, 0, stream>>>(out, sums);
}